// Round 12
// baseline (630.994 us; speedup 1.0000x reference)
//
#include <hip/hip_runtime.h>

#define DEVI __device__ __forceinline__

typedef __attribute__((ext_vector_type(4))) float f32x4;
typedef __attribute__((ext_vector_type(8))) short s16x8;
typedef __attribute__((ext_vector_type(4))) short s16x4;
typedef unsigned short u16;
typedef unsigned int u32;

// B=64, N=256, F=16, H=256, BN=16384, N_ITERS=10
#define WST 288   /* padded k-stride for Wz/Wr/Wh transposed (272 -> 288) */
#define SROW 264  /* k_embed LDS row stride */
#define AST 260   /* act LDS row stride: 520 B rows, b64-pair reads, 0 conflicts (R10) */

// s_waitcnt vmcnt(n) only (gfx9 encoding: expcnt/lgkmcnt = no-wait)
#define WAITVM(n) __builtin_amdgcn_s_waitcnt(((n)&0xF) | 0x70 | 0xF00 | (((n)>>4)<<14))

DEVI u16 f2bf(float x){
  u32 u = __float_as_uint(x);
  u = (u + 0x7fffu + ((u >> 16) & 1u)) >> 16;
  return (u16)u;
}
DEVI float bf2f(u16 v){ return __uint_as_float(((u32)v) << 16); }

DEVI float fsigm(float x){ return __builtin_amdgcn_rcpf(1.f + __builtin_amdgcn_exp2f(-1.442695041f * x)); }
DEVI float ftanh(float x){ float e = __builtin_amdgcn_exp2f(2.885390082f * x); return 1.f - 2.f * __builtin_amdgcn_rcpf(e + 1.f); }

DEVI s16x8 ld8(const u16* p){ return *(const s16x8*)p; }          // 16-B aligned
DEVI s16x8 ldb64p(const u16* p){                                   // 8-B aligned (two b64)
  s16x4 lo = *(const s16x4*)p;
  s16x4 hi = *(const s16x4*)(p + 4);
  s16x8 r;
  r[0]=lo[0]; r[1]=lo[1]; r[2]=lo[2]; r[3]=lo[3];
  r[4]=hi[0]; r[5]=hi[1]; r[6]=hi[2]; r[7]=hi[3];
  return r;
}

DEVI f32x4 ld4bf(const u16* p){
  uint2 v = *(const uint2*)p;
  f32x4 r;
  r[0] = bf2f((u16)(v.x & 0xffff)); r[1] = bf2f((u16)(v.x >> 16));
  r[2] = bf2f((u16)(v.y & 0xffff)); r[3] = bf2f((u16)(v.y >> 16));
  return r;
}

DEVI void st4bf(u16* p, float a, float b, float c, float d){
  uint2 v;
  v.x = (u32)f2bf(a) | ((u32)f2bf(b) << 16);
  v.y = (u32)f2bf(c) | ((u32)f2bf(d) << 16);
  *(uint2*)p = v;
}

#define MFMA(a,b,c) __builtin_amdgcn_mfma_f32_16x16x32_bf16((a),(b),(c),0,0,0)

// Stage one [32 rows][32 k] tile chunk into wave-private LDS via async DMA.
// lanebase = gbase + (lane>>2)*rowStride + swizzled-col (precomputed per phase).
DEVI void dma2(const u16* lanebase, int rowStrideElems, int c, u16* ldsbase){
#pragma unroll
  for(int q = 0; q < 2; q++){
    const u16* g = lanebase + (size_t)q*16*rowStrideElems + c*32;
    __builtin_amdgcn_global_load_lds((__attribute__((address_space(1))) const void*)g,
                                     (__attribute__((address_space(3))) void*)(ldsbase + q*512),
                                     16, 0, 0);
  }
}
// A-fragment read: row t*16+ln, k-quad qd (XOR-swizzle matched to dma2 source)
#define AFRAG(buf, t) ld8(&(buf)[(t)*512 + ln*32 + ((qd ^ ((ln>>1)&3))*8)])

// ---------------------------------------------------------------------------
// Prep (R11)
// ---------------------------------------------------------------------------
__global__ void k_prep(
  const float* __restrict__ jets, const float* __restrict__ dads, const float* __restrict__ W_emb,
  const float* __restrict__ W_msg, const float* __restrict__ Wz, const float* __restrict__ Uz,
  const float* __restrict__ Wr, const float* __restrict__ Ur, const float* __restrict__ Wh,
  const float* __restrict__ Uh, const float* __restrict__ W_r1,
  u16* __restrict__ jp, u16* __restrict__ dadsb, u16* __restrict__ Wet, u16* __restrict__ Wmt,
  u16* __restrict__ Wzt, u16* __restrict__ Uzt, u16* __restrict__ Wrt, u16* __restrict__ Urt,
  u16* __restrict__ Wht, u16* __restrict__ Uht, u16* __restrict__ Wr1t)
{
  int blk = blockIdx.x, tid = threadIdx.x;
  if(blk < 1280){                       // 5 square transposes: read row k coalesced
    int mi = blk >> 8, k = blk & 255, j = tid;
    const float* src; u16* dst;
    switch(mi){
      case 0: src = W_msg; dst = Wmt;  break;
      case 1: src = Uz;    dst = Uzt;  break;
      case 2: src = Ur;    dst = Urt;  break;
      case 3: src = Uh;    dst = Uht;  break;
      default: src = W_r1; dst = Wr1t; break;
    }
    dst[j*256 + k] = f2bf(src[k*256 + j]);
  } else if(blk < 2144){                // Wz/Wr/Wh [272][256] -> [256][288] padded
    int q = blk - 1280; int mi = q / 288; int k = q - mi*288; int j = tid;
    const float* src; u16* dst;
    switch(mi){ case 0: src = Wz; dst = Wzt; break; case 1: src = Wr; dst = Wrt; break; default: src = Wh; dst = Wht; break; }
    dst[j*WST + k] = (k < 272) ? f2bf(src[k*256 + j]) : (u16)0;
  } else if(blk < 2176){                // W_emb [16][256] -> [256][32] padded
    int idx = (blk - 2144)*256 + tid;
    int j = idx >> 5, k = idx & 31;
    Wet[idx] = (k < 16) ? f2bf(W_emb[k*256 + j]) : (u16)0;
  } else if(blk < 4224){                // jets [16384][16] -> [16384][32] padded bf16
    int idx = (blk - 2176)*256 + tid;
    int n = idx >> 5, k = idx & 31;
    jp[idx] = (k < 16) ? f2bf(jets[n*16 + k]) : (u16)0;
  } else {                              // dads cast to bf16, float4-vectorized
    int idx = (blk - 4224)*256 + tid;
    f32x4 v = *(const f32x4*)(dads + (size_t)idx*4);
    st4bf(dadsb + (size_t)idx*4, v[0], v[1], v[2], v[3]);
  }
}

// ---------------------------------------------------------------------------
// Embed (unchanged)
// ---------------------------------------------------------------------------
__global__ __launch_bounds__(256,3) void k_embed(
  u16* __restrict__ h, u16* __restrict__ hmo,
  const u16* __restrict__ jp, const u16* __restrict__ Wet, const float* __restrict__ be,
  const u16* __restrict__ Wmt, const float* __restrict__ bm)
{
  __shared__ u16 hbuf[16*SROW];
  const int tid = threadIdx.x;
  const int wv = tid >> 6, lane = tid & 63, ln = lane & 15, qd = lane >> 4;
  const int n0 = blockIdx.x * 16;
  const int b  = n0 >> 8;
  const int nb = n0 & 255;
  const int nodeA = n0 + ln;

  s16x8 jfr = ld8(jp + (size_t)nodeA*32 + qd*8);
#pragma unroll
  for(int t = 0; t < 4; t++){
    int j0 = (wv*4 + t) * 16;
    f32x4 acc = {0.f,0.f,0.f,0.f};
    s16x8 a = ld8(Wet + (size_t)(j0 + ln)*32 + qd*8);
    acc = MFMA(a, jfr, acc);
    f32x4 bv = *(const f32x4*)(be + j0 + qd*4);
    f32x4 hv;
#pragma unroll
    for(int r = 0; r < 4; r++) hv[r] = ftanh(acc[r] + bv[r]);
    st4bf(h + (size_t)nodeA*256 + j0 + qd*4, hv[0], hv[1], hv[2], hv[3]);
    st4bf(&hbuf[ln*SROW + j0 + qd*4], hv[0], hv[1], hv[2], hv[3]);
  }
  __syncthreads();

  s16x8 af[8];
#pragma unroll
  for(int c = 0; c < 8; c++) af[c] = ld8(&hbuf[ln*SROW + c*32 + qd*8]);
#pragma unroll
  for(int tp = 0; tp < 2; tp++){
    int j0 = (wv*4 + tp*2) * 16, j1 = j0 + 16;
    f32x4 a0 = {0.f,0.f,0.f,0.f}, a1 = {0.f,0.f,0.f,0.f};
#pragma unroll
    for(int c = 0; c < 8; c++){
      a0 = MFMA(af[c], ld8(Wmt + (size_t)(j0 + ln)*256 + c*32 + qd*8), a0);
      a1 = MFMA(af[c], ld8(Wmt + (size_t)(j1 + ln)*256 + c*32 + qd*8), a1);
    }
    float b0 = bm[j0 + ln], b1 = bm[j1 + ln];
    st4bf(hmo + (size_t)(b*256 + j0 + ln)*256 + nb + qd*4, a0[0]+b0, a0[1]+b0, a0[2]+b0, a0[3]+b0);
    st4bf(hmo + (size_t)(b*256 + j1 + ln)*256 + nb + qd*4, a1[0]+b1, a1[1]+b1, a1[2]+b1, a1[3]+b1);
  }
}

// ---------------------------------------------------------------------------
// k_gru v14: phase-merged. 64 nodes/block, 256 blocks, 512 thr (8 waves).
//  stage1: m = tanh(dads@hm)            [DMA-staged, 8 MFMA/chunk]
//  phase A: racc=m@Wr+h@Ur, zacc=m@Wz+h@Uz  [JIT A-loads, 32 MFMA/chunk]
//  phase B: gacc=m@Wh+rh@Uh             [DMA-staged 2 streams, 16 MFMA/chunk]
//  msg: hm_out = h_new@Wmsg             [DMA-staged, 8 MFMA/chunk]
// Acts at AST=260 + ldb64p (R10-proven 0 conflicts).
// ---------------------------------------------------------------------------
__global__ __launch_bounds__(512,1) void k_gru(
  u16* __restrict__ h,
  const u16* __restrict__ hmi, u16* __restrict__ hmo,
  const u16* __restrict__ dadsb, const u16* __restrict__ jp,
  const u16* __restrict__ Wzt, const u16* __restrict__ Wrt, const u16* __restrict__ Wht,
  const u16* __restrict__ Uzt, const u16* __restrict__ Urt, const u16* __restrict__ Uht,
  const u16* __restrict__ Wmt,
  const float* __restrict__ bz, const float* __restrict__ br, const float* __restrict__ bhb,
  const float* __restrict__ bm)
{
  __shared__ u16 smM[64*AST];                       // m, later h_new
  __shared__ u16 smB[64*AST];                       // rh
  __shared__ __align__(16) u16 stg[8][2][2][1024];  // [wave][buf][mat] 64 KB
  const int tid = threadIdx.x;
  const int wv = tid >> 6, lane = tid & 63, ln = lane & 15, qd = lane >> 4;
  const int blk   = blockIdx.x;
  const int batch = (blk & 7) * 8 + (blk >> 5);
  const int group = (blk >> 3) & 3;
  const int n0 = batch * 256 + group * 64;
  const int b  = batch;
  const int nb = group * 64;
  const int j0w = wv * 32;

  u16* s0 = &stg[wv][0][0][0];
  u16* s1 = &stg[wv][1][0][0];
  u16* u0 = &stg[wv][0][1][0];
  u16* u1 = &stg[wv][1][1][0];

  // per-lane DMA source addressing (row = lane>>2, XOR-swizzled col)
  const int rw = lane >> 2;
  const int cs = ((lane & 3) ^ ((lane >> 3) & 3)) * 8;

  // stage1 chunk-0 prefetch ASAP
  const u16* laneA = hmi + (size_t)(b*256 + j0w + rw)*256 + cs;
  dma2(laneA, 256, 0, s0);

  s16x8 jB[4];
#pragma unroll
  for(int i = 0; i < 4; i++) jB[i] = ld8(jp + (size_t)(n0 + i*16 + ln)*32 + qd*8);

  // ================= stage1: m = tanh(dads @ hm) =================
  {
    f32x4 acc[2][4];
#pragma unroll
    for(int t = 0; t < 2; t++)
#pragma unroll
      for(int i = 0; i < 4; i++) acc[t][i] = (f32x4){0.f,0.f,0.f,0.f};
    s16x8 Bf[4], Bn[4];
#pragma unroll
    for(int i = 0; i < 4; i++) Bf[i] = ld8(dadsb + (size_t)(n0 + i*16 + ln)*256 + qd*8);
#pragma unroll
    for(int c = 0; c < 8; c++){
      u16* cur = (c & 1) ? s1 : s0;
      if(c < 7){
        dma2(laneA, 256, c+1, (c & 1) ? s0 : s1);
#pragma unroll
        for(int i = 0; i < 4; i++) Bn[i] = ld8(dadsb + (size_t)(n0 + i*16 + ln)*256 + (c+1)*32 + qd*8);
        WAITVM(6);
      } else {
        WAITVM(0);
      }
#pragma unroll
      for(int t = 0; t < 2; t++){
        s16x8 A = AFRAG(cur, t);
#pragma unroll
        for(int i = 0; i < 4; i++) acc[t][i] = MFMA(A, Bf[i], acc[t][i]);
      }
      if(c < 7){
#pragma unroll
        for(int i = 0; i < 4; i++) Bf[i] = Bn[i];
      }
    }
#pragma unroll
    for(int t = 0; t < 2; t++)
#pragma unroll
      for(int i = 0; i < 4; i++)
        st4bf(&smM[(i*16 + ln)*AST + j0w + t*16 + qd*4],
              ftanh(acc[t][i][0]), ftanh(acc[t][i][1]), ftanh(acc[t][i][2]), ftanh(acc[t][i][3]));
  }
  __syncthreads();

  // ====== phase A: racc = m@Wr + h@Ur (+jets tail); zacc = m@Wz + h@Uz (+tail) ======
  f32x4 racc[2][4], zacc[2][4], gacc[2][4];
#pragma unroll
  for(int t = 0; t < 2; t++)
#pragma unroll
    for(int i = 0; i < 4; i++){
      racc[t][i] = (f32x4){0.f,0.f,0.f,0.f};
      zacc[t][i] = (f32x4){0.f,0.f,0.f,0.f};
      gacc[t][i] = (f32x4){0.f,0.f,0.f,0.f};
    }
  {
#pragma unroll
    for(int c = 0; c < 8; c++){
      s16x8 Awr[2], Awz[2], Aur[2], Auz[2];
#pragma unroll
      for(int t = 0; t < 2; t++){
        Awr[t] = ld8(Wrt + (size_t)(j0w + t*16 + ln)*WST + c*32 + qd*8);
        Awz[t] = ld8(Wzt + (size_t)(j0w + t*16 + ln)*WST + c*32 + qd*8);
        Aur[t] = ld8(Urt + (size_t)(j0w + t*16 + ln)*256 + c*32 + qd*8);
        Auz[t] = ld8(Uzt + (size_t)(j0w + t*16 + ln)*256 + c*32 + qd*8);
      }
      s16x8 Bh[4], Bm[4];
#pragma unroll
      for(int i = 0; i < 4; i++) Bh[i] = ld8(h + (size_t)(n0 + i*16 + ln)*256 + c*32 + qd*8);
#pragma unroll
      for(int i = 0; i < 4; i++) Bm[i] = ldb64p(&smM[(i*16 + ln)*AST + c*32 + qd*8]);
      // m-consuming MFMAs first (LDS operands land first), h-consuming after
#pragma unroll
      for(int t = 0; t < 2; t++)
#pragma unroll
        for(int i = 0; i < 4; i++){
          racc[t][i] = MFMA(Awr[t], Bm[i], racc[t][i]);
          zacc[t][i] = MFMA(Awz[t], Bm[i], zacc[t][i]);
        }
#pragma unroll
      for(int t = 0; t < 2; t++)
#pragma unroll
        for(int i = 0; i < 4; i++){
          racc[t][i] = MFMA(Aur[t], Bh[i], racc[t][i]);
          zacc[t][i] = MFMA(Auz[t], Bh[i], zacc[t][i]);
        }
    }
    // jets tails
#pragma unroll
    for(int t = 0; t < 2; t++){
      s16x8 Ajr = ld8(Wrt + (size_t)(j0w + t*16 + ln)*WST + 256 + qd*8);
      s16x8 Ajz = ld8(Wzt + (size_t)(j0w + t*16 + ln)*WST + 256 + qd*8);
#pragma unroll
      for(int i = 0; i < 4; i++){
        racc[t][i] = MFMA(Ajr, jB[i], racc[t][i]);
        zacc[t][i] = MFMA(Ajz, jB[i], zacc[t][i]);
      }
    }
    // epilogue A: rh = sig(racc + br) * h -> smB
#pragma unroll
    for(int t = 0; t < 2; t++){
      f32x4 bv = *(const f32x4*)(br + j0w + t*16 + qd*4);
#pragma unroll
      for(int i = 0; i < 4; i++){
        f32x4 hv = ld4bf(h + (size_t)(n0 + i*16 + ln)*256 + j0w + t*16 + qd*4);
        st4bf(&smB[(i*16 + ln)*AST + j0w + t*16 + qd*4],
              fsigm(racc[t][i][0]+bv[0])*hv[0], fsigm(racc[t][i][1]+bv[1])*hv[1],
              fsigm(racc[t][i][2]+bv[2])*hv[2], fsigm(racc[t][i][3]+bv[3])*hv[3]);
      }
    }
  }
  // phase-B chunk-0 prefetch BEFORE the barrier (wave-private buffers)
  const u16* laneWh = Wht + (size_t)(j0w + rw)*WST + cs;
  const u16* laneUh = Uht + (size_t)(j0w + rw)*256 + cs;
  dma2(laneWh, WST, 0, s0);
  dma2(laneUh, 256, 0, u0);
  __syncthreads();

  // ====== phase B: gacc = m@Wh + rh@Uh (+jets tail) ======
  {
#pragma unroll
    for(int c = 0; c < 8; c++){
      u16* cw = (c & 1) ? s1 : s0;
      u16* cu = (c & 1) ? u1 : u0;
      if(c < 7){
        dma2(laneWh, WST, c+1, (c & 1) ? s0 : s1);
        dma2(laneUh, 256, c+1, (c & 1) ? u0 : u1);
        WAITVM(4);
      } else {
        WAITVM(0);
      }
      s16x8 Bm[4], Brh[4];
#pragma unroll
      for(int i = 0; i < 4; i++){
        Bm[i]  = ldb64p(&smM[(i*16 + ln)*AST + c*32 + qd*8]);
        Brh[i] = ldb64p(&smB[(i*16 + ln)*AST + c*32 + qd*8]);
      }
#pragma unroll
      for(int t = 0; t < 2; t++){
        s16x8 Aw = AFRAG(cw, t);
#pragma unroll
        for(int i = 0; i < 4; i++) gacc[t][i] = MFMA(Aw, Bm[i], gacc[t][i]);
      }
#pragma unroll
      for(int t = 0; t < 2; t++){
        s16x8 Au = AFRAG(cu, t);
#pragma unroll
        for(int i = 0; i < 4; i++) gacc[t][i] = MFMA(Au, Brh[i], gacc[t][i]);
      }
    }
#pragma unroll
    for(int t = 0; t < 2; t++){
      s16x8 Ajh = ld8(Wht + (size_t)(j0w + t*16 + ln)*WST + 256 + qd*8);
#pragma unroll
      for(int i = 0; i < 4; i++) gacc[t][i] = MFMA(Ajh, jB[i], gacc[t][i]);
    }
  }
  __syncthreads();   // all smM/smB reads complete before epilogue overwrites smM

  // ================= epilogue: h_new = h + z*(tanh(g)-h) =================
#pragma unroll
  for(int t = 0; t < 2; t++){
    f32x4 bzv = *(const f32x4*)(bz + j0w + t*16 + qd*4);
    f32x4 bhv = *(const f32x4*)(bhb + j0w + t*16 + qd*4);
#pragma unroll
    for(int i = 0; i < 4; i++){
      f32x4 hv = ld4bf(h + (size_t)(n0 + i*16 + ln)*256 + j0w + t*16 + qd*4);
      f32x4 hn;
#pragma unroll
      for(int r = 0; r < 4; r++){
        float z  = fsigm(zacc[t][i][r] + bzv[r]);
        float th = ftanh(gacc[t][i][r] + bhv[r]);
        hn[r] = hv[r] + z * (th - hv[r]);
      }
      st4bf(h + (size_t)(n0 + i*16 + ln)*256 + j0w + t*16 + qd*4, hn[0], hn[1], hn[2], hn[3]);
      st4bf(&smM[(i*16 + ln)*AST + j0w + t*16 + qd*4], hn[0], hn[1], hn[2], hn[3]);
    }
  }
  // msg chunk-0 prefetch BEFORE the barrier
  const u16* laneWm = Wmt + (size_t)(j0w + rw)*256 + cs;
  dma2(laneWm, 256, 0, s0);
  __syncthreads();

  // ================= msg: hm_out = h_new @ W_msg + b_msg -> [b][h][node] =================
  {
    f32x4 acc[2][4];
#pragma unroll
    for(int t = 0; t < 2; t++)
#pragma unroll
      for(int i = 0; i < 4; i++) acc[t][i] = (f32x4){0.f,0.f,0.f,0.f};
#pragma unroll
    for(int c = 0; c < 8; c++){
      u16* cur = (c & 1) ? s1 : s0;
      if(c < 7){
        dma2(laneWm, 256, c+1, (c & 1) ? s0 : s1);
        WAITVM(2);
      } else {
        WAITVM(0);
      }
      s16x8 Bf[4];
#pragma unroll
      for(int i = 0; i < 4; i++) Bf[i] = ldb64p(&smM[(i*16 + ln)*AST + c*32 + qd*8]);
#pragma unroll
      for(int t = 0; t < 2; t++){
        s16x8 A = AFRAG(cur, t);
#pragma unroll
        for(int i = 0; i < 4; i++) acc[t][i] = MFMA(A, Bf[i], acc[t][i]);
      }
    }
#pragma unroll
    for(int t = 0; t < 2; t++){
      f32x4 bmv = *(const f32x4*)(bm + j0w + t*16 + qd*4);
#pragma unroll
      for(int i = 0; i < 4; i++){
#pragma unroll
        for(int r = 0; r < 4; r++){
          hmo[(size_t)(b*256 + j0w + t*16 + qd*4 + r)*256 + nb + i*16 + ln] =
            f2bf(acc[t][i][r] + bmv[r]);
        }
      }
    }
  }
}

// ---------------------------------------------------------------------------
// Readout stage 1: t = tanh(h@W_r1 + b_r1), bf16 [BN][256]
// ---------------------------------------------------------------------------
__global__ __launch_bounds__(256,3) void k_t(
  const u16* __restrict__ h, u16* __restrict__ t_out,
  const u16* __restrict__ Wr1t, const float* __restrict__ br1)
{
  const int tid = threadIdx.x;
  const int wv = tid >> 6, lane = tid & 63, ln = lane & 15, qd = lane >> 4;
  const int n0 = blockIdx.x * 16;
  const int nodeA = n0 + ln;

  s16x8 hfr[8];
#pragma unroll
  for(int c = 0; c < 8; c++) hfr[c] = ld8(h + (size_t)nodeA*256 + c*32 + qd*8);
#pragma unroll
  for(int tp = 0; tp < 2; tp++){
    int j0 = (wv*4 + tp*2) * 16, j1 = j0 + 16;
    f32x4 a0 = {0.f,0.f,0.f,0.f}, a1 = {0.f,0.f,0.f,0.f};
#pragma unroll
    for(int c = 0; c < 8; c++){
      a0 = MFMA(ld8(Wr1t + (size_t)(j0 + ln)*256 + c*32 + qd*8), hfr[c], a0);
      a1 = MFMA(ld8(Wr1t + (size_t)(j1 + ln)*256 + c*32 + qd*8), hfr[c], a1);
    }
    f32x4 b0 = *(const f32x4*)(br1 + j0 + qd*4);
    f32x4 b1 = *(const f32x4*)(br1 + j1 + qd*4);
    st4bf(t_out + (size_t)nodeA*256 + j0 + qd*4,
          ftanh(a0[0]+b0[0]), ftanh(a0[1]+b0[1]), ftanh(a0[2]+b0[2]), ftanh(a0[3]+b0[3]));
    st4bf(t_out + (size_t)nodeA*256 + j1 + qd*4,
          ftanh(a1[0]+b1[0]), ftanh(a1[1]+b1[1]), ftanh(a1[2]+b1[2]), ftanh(a1[3]+b1[3]));
  }
}

// Readout: fused node-sum + final matmul. 64 blocks (one per batch) x 256 thr.
__global__ void k_red(const u16* __restrict__ t, const float* __restrict__ W_r2,
                      const float* __restrict__ b_r2, float* __restrict__ out){
  __shared__ float s[256];
  int b = blockIdx.x, k = threadIdx.x;
  float acc = 0.f;
  for(int n = 0; n < 256; n++) acc += bf2f(t[(size_t)(b*256 + n)*256 + k]);
  s[k] = acc;
  __syncthreads();
  int j = threadIdx.x;
  float o = 256.f * b_r2[j];
  for(int k2 = 0; k2 < 256; k2++) o += s[k2] * W_r2[k2*256 + j];
  out[b*256 + j] = o;
}

extern "C" void kernel_launch(void* const* d_in, const int* in_sizes, int n_in,
                              void* d_out, int out_size, void* d_ws, size_t ws_size,
                              hipStream_t stream)
{
  const float* jets  = (const float*)d_in[0];
  const float* dads  = (const float*)d_in[1];
  const float* W_emb = (const float*)d_in[2];
  const float* b_emb = (const float*)d_in[3];
  const float* W_msg = (const float*)d_in[4];
  const float* b_msg = (const float*)d_in[5];
  const float* Wz    = (const float*)d_in[6];
  const float* Uz    = (const float*)d_in[7];
  const float* bz    = (const float*)d_in[8];
  const float* Wr    = (const float*)d_in[9];
  const float* Ur    = (const float*)d_in[10];
  const float* br    = (const float*)d_in[11];
  const float* Wh    = (const float*)d_in[12];
  const float* Uh    = (const float*)d_in[13];
  const float* bh    = (const float*)d_in[14];
  const float* W_r1  = (const float*)d_in[15];
  const float* b_r1  = (const float*)d_in[16];
  const float* W_r2  = (const float*)d_in[17];
  const float* b_r2  = (const float*)d_in[18];

  char* ws = (char*)d_ws;
  u16* h      = (u16*)(ws);                    // 8 MB  [16384][256] bf16
  u16* hmA    = (u16*)(ws + 8388608);          // 8 MB  [64][256 h][256 node] bf16
  u16* hmB    = (u16*)(ws + 16777216);         // 8 MB
  u16* dadsb  = (u16*)(ws + 25165824);         // 8 MB  [16384][256] bf16
  u16* jp     = (u16*)(ws + 33554432);         // 1 MB  [16384][32] bf16
  u16* Wmt    = (u16*)(ws + 34603008);
  u16* Uzt    = (u16*)(ws + 34734080);
  u16* Urt    = (u16*)(ws + 34865152);
  u16* Uht    = (u16*)(ws + 34996224);
  u16* Wr1t   = (u16*)(ws + 35127296);
  u16* Wzt    = (u16*)(ws + 35258368);
  u16* Wrt    = (u16*)(ws + 35405824);
  u16* Wht    = (u16*)(ws + 35553280);
  u16* Wet    = (u16*)(ws + 35700736);
  float* outp = (float*)d_out;

  k_prep<<<8320, 256, 0, stream>>>(jets, dads, W_emb, W_msg, Wz, Uz, Wr, Ur, Wh, Uh, W_r1,
                                   jp, dadsb, Wet, Wmt, Wzt, Uzt, Wrt, Urt, Wht, Uht, Wr1t);
  k_embed<<<1024, 256, 0, stream>>>(h, hmA, jp, Wet, b_emb, Wmt, b_msg);
  for(int it = 0; it < 10; ++it){
    const u16* hin = (it & 1) ? hmB : hmA;
    u16* hout      = (it & 1) ? hmA : hmB;
    k_gru<<<256, 512, 0, stream>>>(h, hin, hout, dadsb, jp,
                                   Wzt, Wrt, Wht, Uzt, Urt, Uht, Wmt,
                                   bz, br, bh, b_msg);
  }
  // it=9 wrote hmA, so hmB is free: reuse as t-buffer
  k_t<<<1024, 256, 0, stream>>>(h, hmB, Wr1t, b_r1);
  k_red<<<64, 256, 0, stream>>>(hmB, W_r2, b_r2, outp);
}

// Round 13
// 558.942 us; speedup vs baseline: 1.1289x; 1.1289x over previous
//
#include <hip/hip_runtime.h>

#define DEVI __device__ __forceinline__

typedef __attribute__((ext_vector_type(4))) float f32x4;
typedef __attribute__((ext_vector_type(8))) short s16x8;
typedef __attribute__((ext_vector_type(4))) short s16x4;
typedef unsigned short u16;
typedef unsigned int u32;

// B=64, N=256, F=16, H=256, BN=16384, N_ITERS=10
#define WST 288   /* padded k-stride for Wz/Wr/Wh transposed (272 -> 288) */
#define SROW 264  /* k_embed LDS row stride */
#define AST 260   /* act LDS row stride: 520 B rows, b64-pair reads, 0 conflicts (R10) */

// s_waitcnt vmcnt(n) only (gfx9 encoding: expcnt/lgkmcnt = no-wait)
#define WAITVM(n) __builtin_amdgcn_s_waitcnt(((n)&0xF) | 0x70 | 0xF00 | (((n)>>4)<<14))

DEVI u16 f2bf(float x){
  u32 u = __float_as_uint(x);
  u = (u + 0x7fffu + ((u >> 16) & 1u)) >> 16;
  return (u16)u;
}
DEVI float bf2f(u16 v){ return __uint_as_float(((u32)v) << 16); }

DEVI float fsigm(float x){ return __builtin_amdgcn_rcpf(1.f + __builtin_amdgcn_exp2f(-1.442695041f * x)); }
DEVI float ftanh(float x){ float e = __builtin_amdgcn_exp2f(2.885390082f * x); return 1.f - 2.f * __builtin_amdgcn_rcpf(e + 1.f); }

DEVI s16x8 ld8(const u16* p){ return *(const s16x8*)p; }          // 16-B aligned
DEVI s16x8 ldb64p(const u16* p){                                   // 8-B aligned (two b64)
  s16x4 lo = *(const s16x4*)p;
  s16x4 hi = *(const s16x4*)(p + 4);
  s16x8 r;
  r[0]=lo[0]; r[1]=lo[1]; r[2]=lo[2]; r[3]=lo[3];
  r[4]=hi[0]; r[5]=hi[1]; r[6]=hi[2]; r[7]=hi[3];
  return r;
}

DEVI f32x4 ld4bf(const u16* p){
  uint2 v = *(const uint2*)p;
  f32x4 r;
  r[0] = bf2f((u16)(v.x & 0xffff)); r[1] = bf2f((u16)(v.x >> 16));
  r[2] = bf2f((u16)(v.y & 0xffff)); r[3] = bf2f((u16)(v.y >> 16));
  return r;
}

DEVI void st4bf(u16* p, float a, float b, float c, float d){
  uint2 v;
  v.x = (u32)f2bf(a) | ((u32)f2bf(b) << 16);
  v.y = (u32)f2bf(c) | ((u32)f2bf(d) << 16);
  *(uint2*)p = v;
}

#define MFMA(a,b,c) __builtin_amdgcn_mfma_f32_16x16x32_bf16((a),(b),(c),0,0,0)

// Stage one [64 rows][32 k] tile chunk into wave-private LDS via async DMA
// (4 x 1KB instrs). Source col XOR-swizzled (col ^= (row>>1)&3) so AFRAG's
// ds_read_b128 lands 2-way per bank (R10-measured: 0 conflicts).
DEVI void dma4(const u16* lanebase, int rowStrideElems, int c, u16* ldsbase){
#pragma unroll
  for(int q = 0; q < 4; q++){
    const u16* g = lanebase + (size_t)q*16*rowStrideElems + c*32;
    __builtin_amdgcn_global_load_lds((__attribute__((address_space(1))) const void*)g,
                                     (__attribute__((address_space(3))) void*)(ldsbase + q*512),
                                     16, 0, 0);
  }
}
// A-fragment read: subtile t (16 rows), row ln, k-quad qd (swizzle-matched)
#define AFRAG(buf, t) ld8(&(buf)[(t)*512 + ln*32 + ((qd ^ ((ln>>1)&3))*8)])

// ---------------------------------------------------------------------------
// Prep (coalesced-read transposes)
// ---------------------------------------------------------------------------
__global__ void k_prep(
  const float* __restrict__ jets, const float* __restrict__ dads, const float* __restrict__ W_emb,
  const float* __restrict__ W_msg, const float* __restrict__ Wz, const float* __restrict__ Uz,
  const float* __restrict__ Wr, const float* __restrict__ Ur, const float* __restrict__ Wh,
  const float* __restrict__ Uh, const float* __restrict__ W_r1,
  u16* __restrict__ jp, u16* __restrict__ dadsb, u16* __restrict__ Wet, u16* __restrict__ Wmt,
  u16* __restrict__ Wzt, u16* __restrict__ Uzt, u16* __restrict__ Wrt, u16* __restrict__ Urt,
  u16* __restrict__ Wht, u16* __restrict__ Uht, u16* __restrict__ Wr1t)
{
  int blk = blockIdx.x, tid = threadIdx.x;
  if(blk < 1280){
    int mi = blk >> 8, k = blk & 255, j = tid;
    const float* src; u16* dst;
    switch(mi){
      case 0: src = W_msg; dst = Wmt;  break;
      case 1: src = Uz;    dst = Uzt;  break;
      case 2: src = Ur;    dst = Urt;  break;
      case 3: src = Uh;    dst = Uht;  break;
      default: src = W_r1; dst = Wr1t; break;
    }
    dst[j*256 + k] = f2bf(src[k*256 + j]);
  } else if(blk < 2144){
    int q = blk - 1280; int mi = q / 288; int k = q - mi*288; int j = tid;
    const float* src; u16* dst;
    switch(mi){ case 0: src = Wz; dst = Wzt; break; case 1: src = Wr; dst = Wrt; break; default: src = Wh; dst = Wht; break; }
    dst[j*WST + k] = (k < 272) ? f2bf(src[k*256 + j]) : (u16)0;
  } else if(blk < 2176){
    int idx = (blk - 2144)*256 + tid;
    int j = idx >> 5, k = idx & 31;
    Wet[idx] = (k < 16) ? f2bf(W_emb[k*256 + j]) : (u16)0;
  } else if(blk < 4224){
    int idx = (blk - 2176)*256 + tid;
    int n = idx >> 5, k = idx & 31;
    jp[idx] = (k < 16) ? f2bf(jets[n*16 + k]) : (u16)0;
  } else {
    int idx = (blk - 4224)*256 + tid;
    f32x4 v = *(const f32x4*)(dads + (size_t)idx*4);
    st4bf(dadsb + (size_t)idx*4, v[0], v[1], v[2], v[3]);
  }
}

// ---------------------------------------------------------------------------
// Embed (unchanged)
// ---------------------------------------------------------------------------
__global__ __launch_bounds__(256,3) void k_embed(
  u16* __restrict__ h, u16* __restrict__ hmo,
  const u16* __restrict__ jp, const u16* __restrict__ Wet, const float* __restrict__ be,
  const u16* __restrict__ Wmt, const float* __restrict__ bm)
{
  __shared__ u16 hbuf[16*SROW];
  const int tid = threadIdx.x;
  const int wv = tid >> 6, lane = tid & 63, ln = lane & 15, qd = lane >> 4;
  const int n0 = blockIdx.x * 16;
  const int b  = n0 >> 8;
  const int nb = n0 & 255;
  const int nodeA = n0 + ln;

  s16x8 jfr = ld8(jp + (size_t)nodeA*32 + qd*8);
#pragma unroll
  for(int t = 0; t < 4; t++){
    int j0 = (wv*4 + t) * 16;
    f32x4 acc = {0.f,0.f,0.f,0.f};
    s16x8 a = ld8(Wet + (size_t)(j0 + ln)*32 + qd*8);
    acc = MFMA(a, jfr, acc);
    f32x4 bv = *(const f32x4*)(be + j0 + qd*4);
    f32x4 hv;
#pragma unroll
    for(int r = 0; r < 4; r++) hv[r] = ftanh(acc[r] + bv[r]);
    st4bf(h + (size_t)nodeA*256 + j0 + qd*4, hv[0], hv[1], hv[2], hv[3]);
    st4bf(&hbuf[ln*SROW + j0 + qd*4], hv[0], hv[1], hv[2], hv[3]);
  }
  __syncthreads();

  s16x8 af[8];
#pragma unroll
  for(int c = 0; c < 8; c++) af[c] = ld8(&hbuf[ln*SROW + c*32 + qd*8]);
#pragma unroll
  for(int tp = 0; tp < 2; tp++){
    int j0 = (wv*4 + tp*2) * 16, j1 = j0 + 16;
    f32x4 a0 = {0.f,0.f,0.f,0.f}, a1 = {0.f,0.f,0.f,0.f};
#pragma unroll
    for(int c = 0; c < 8; c++){
      a0 = MFMA(af[c], ld8(Wmt + (size_t)(j0 + ln)*256 + c*32 + qd*8), a0);
      a1 = MFMA(af[c], ld8(Wmt + (size_t)(j1 + ln)*256 + c*32 + qd*8), a1);
    }
    float b0 = bm[j0 + ln], b1 = bm[j1 + ln];
    st4bf(hmo + (size_t)(b*256 + j0 + ln)*256 + nb + qd*4, a0[0]+b0, a0[1]+b0, a0[2]+b0, a0[3]+b0);
    st4bf(hmo + (size_t)(b*256 + j1 + ln)*256 + nb + qd*4, a1[0]+b1, a1[1]+b1, a1[2]+b1, a1[3]+b1);
  }
}

// ---------------------------------------------------------------------------
// k_gru v15: R9 fat-wave geometry (256 thr, 4 waves, jt=4 x nt=4 = 16 acc
// chains/pass) + R10's conflict-free XOR staging swizzle + cross-barrier
// chunk-0 DMA prefetch (issued AFTER epilogues so compiler vm-waits on
// epilogue loads don't drain the prefetch). 5-phase structure (R12 merge
// regressed via L2 thrash — reverted).
// ---------------------------------------------------------------------------
__global__ __launch_bounds__(256,1) void k_gru(
  u16* __restrict__ h,
  const u16* __restrict__ hmi, u16* __restrict__ hmo,
  const u16* __restrict__ dadsb, const u16* __restrict__ jp,
  const u16* __restrict__ Wzt, const u16* __restrict__ Wrt, const u16* __restrict__ Wht,
  const u16* __restrict__ Uzt, const u16* __restrict__ Urt, const u16* __restrict__ Uht,
  const u16* __restrict__ Wmt,
  const float* __restrict__ bz, const float* __restrict__ br, const float* __restrict__ bhb,
  const float* __restrict__ bm)
{
  __shared__ u16 smM[64*AST];                       // m, later h_new
  __shared__ u16 smB[64*AST];                       // rh
  __shared__ __align__(16) u16 stg[4][2][2][2048];  // [wave][buf][mat] 64 KB
  const int tid = threadIdx.x;
  const int wv = tid >> 6, lane = tid & 63, ln = lane & 15, qd = lane >> 4;
  const int blk   = blockIdx.x;
  const int batch = (blk & 7) * 8 + (blk >> 5);
  const int group = (blk >> 3) & 3;
  const int n0 = batch * 256 + group * 64;
  const int b  = batch;
  const int nb = group * 64;
  const int j0w = wv * 64;                 // wave's 64-wide j-quarter

  u16* s0 = &stg[wv][0][0][0];
  u16* s1 = &stg[wv][1][0][0];
  u16* u0 = &stg[wv][0][1][0];
  u16* u1 = &stg[wv][1][1][0];

  // per-lane DMA source addressing (row = lane>>2, XOR-swizzled col)
  const int rw = lane >> 2;
  const int cs = ((lane & 3) ^ ((lane >> 3) & 3)) * 8;

  // stage1 chunk-0 prefetch ASAP
  const u16* laneA = hmi + (size_t)(b*256 + j0w + rw)*256 + cs;
  dma4(laneA, 256, 0, s0);

  s16x8 jB[4];
#pragma unroll
  for(int i = 0; i < 4; i++) jB[i] = ld8(jp + (size_t)(n0 + i*16 + ln)*32 + qd*8);

  // ================= stage1: m = tanh(dads @ hm) =================
  {
    f32x4 acc[4][4];
#pragma unroll
    for(int t = 0; t < 4; t++)
#pragma unroll
      for(int i = 0; i < 4; i++) acc[t][i] = (f32x4){0.f,0.f,0.f,0.f};
    s16x8 Bf[4], Bn[4];
#pragma unroll
    for(int i = 0; i < 4; i++) Bf[i] = ld8(dadsb + (size_t)(n0 + i*16 + ln)*256 + qd*8);
#pragma unroll
    for(int c = 0; c < 8; c++){
      u16* cur = (c & 1) ? s1 : s0;
      if(c < 7){
        dma4(laneA, 256, c+1, (c & 1) ? s0 : s1);
#pragma unroll
        for(int i = 0; i < 4; i++) Bn[i] = ld8(dadsb + (size_t)(n0 + i*16 + ln)*256 + (c+1)*32 + qd*8);
        WAITVM(8);
      } else {
        WAITVM(0);
      }
#pragma unroll
      for(int t = 0; t < 4; t++){
        s16x8 A = AFRAG(cur, t);
#pragma unroll
        for(int i = 0; i < 4; i++) acc[t][i] = MFMA(A, Bf[i], acc[t][i]);
      }
      if(c < 7){
#pragma unroll
        for(int i = 0; i < 4; i++) Bf[i] = Bn[i];
      }
    }
#pragma unroll
    for(int t = 0; t < 4; t++)
#pragma unroll
      for(int i = 0; i < 4; i++)
        st4bf(&smM[(i*16 + ln)*AST + j0w + t*16 + qd*4],
              ftanh(acc[t][i][0]), ftanh(acc[t][i][1]), ftanh(acc[t][i][2]), ftanh(acc[t][i][3]));
  }
  // r-phase chunk-0 prefetch before the barrier (wave-private buffers)
  const u16* laneWr = Wrt + (size_t)(j0w + rw)*WST + cs;
  const u16* laneUr = Urt + (size_t)(j0w + rw)*256 + cs;
  dma4(laneWr, WST, 0, s0);
  dma4(laneUr, 256, 0, u0);
  __syncthreads();

  // ================= r-pass: rh = sig(m@Wr + jets@Wr' + h@Ur + br)*h =================
  {
    f32x4 acc[4][4];
#pragma unroll
    for(int t = 0; t < 4; t++)
#pragma unroll
      for(int i = 0; i < 4; i++) acc[t][i] = (f32x4){0.f,0.f,0.f,0.f};
    s16x8 Aj[4];
#pragma unroll
    for(int t = 0; t < 4; t++) Aj[t] = ld8(Wrt + (size_t)(j0w + t*16 + ln)*WST + 256 + qd*8);
    s16x8 Bh[4], Bn[4];
#pragma unroll
    for(int i = 0; i < 4; i++) Bh[i] = ld8(h + (size_t)(n0 + i*16 + ln)*256 + qd*8);
#pragma unroll
    for(int c = 0; c < 8; c++){
      u16* cw = (c & 1) ? s1 : s0;
      u16* cu = (c & 1) ? u1 : u0;
      if(c < 7){
        dma4(laneWr, WST, c+1, (c & 1) ? s0 : s1);
        dma4(laneUr, 256, c+1, (c & 1) ? u0 : u1);
#pragma unroll
        for(int i = 0; i < 4; i++) Bn[i] = ld8(h + (size_t)(n0 + i*16 + ln)*256 + (c+1)*32 + qd*8);
        WAITVM(12);
      } else {
        WAITVM(0);
      }
      s16x8 Bm[4];
#pragma unroll
      for(int i = 0; i < 4; i++) Bm[i] = ldb64p(&smM[(i*16 + ln)*AST + c*32 + qd*8]);
#pragma unroll
      for(int t = 0; t < 4; t++){
        s16x8 Aw = AFRAG(cw, t);
#pragma unroll
        for(int i = 0; i < 4; i++) acc[t][i] = MFMA(Aw, Bm[i], acc[t][i]);
      }
#pragma unroll
      for(int t = 0; t < 4; t++){
        s16x8 Au = AFRAG(cu, t);
#pragma unroll
        for(int i = 0; i < 4; i++) acc[t][i] = MFMA(Au, Bh[i], acc[t][i]);
      }
      if(c < 7){
#pragma unroll
        for(int i = 0; i < 4; i++) Bh[i] = Bn[i];
      }
    }
#pragma unroll
    for(int t = 0; t < 4; t++)
#pragma unroll
      for(int i = 0; i < 4; i++) acc[t][i] = MFMA(Aj[t], jB[i], acc[t][i]);
#pragma unroll
    for(int t = 0; t < 4; t++){
      f32x4 bv = *(const f32x4*)(br + j0w + t*16 + qd*4);
#pragma unroll
      for(int i = 0; i < 4; i++){
        f32x4 hv = ld4bf(h + (size_t)(n0 + i*16 + ln)*256 + j0w + t*16 + qd*4);
        st4bf(&smB[(i*16 + ln)*AST + j0w + t*16 + qd*4],
              fsigm(acc[t][i][0]+bv[0])*hv[0], fsigm(acc[t][i][1]+bv[1])*hv[1],
              fsigm(acc[t][i][2]+bv[2])*hv[2], fsigm(acc[t][i][3]+bv[3])*hv[3]);
      }
    }
  }
  // z-phase chunk-0 prefetch (after epilogue so its hv-load waits don't drain us)
  const u16* laneWz = Wzt + (size_t)(j0w + rw)*WST + cs;
  const u16* laneUz = Uzt + (size_t)(j0w + rw)*256 + cs;
  dma4(laneWz, WST, 0, s0);
  dma4(laneUz, 256, 0, u0);
  __syncthreads();

  // ================= z-phase: zacc = m@Wz + jets@Wz' + h@Uz =================
  f32x4 zacc[4][4], gacc[4][4];
#pragma unroll
  for(int t = 0; t < 4; t++)
#pragma unroll
    for(int i = 0; i < 4; i++) zacc[t][i] = (f32x4){0.f,0.f,0.f,0.f};
  {
    s16x8 Aj[4];
#pragma unroll
    for(int t = 0; t < 4; t++) Aj[t] = ld8(Wzt + (size_t)(j0w + t*16 + ln)*WST + 256 + qd*8);
    s16x8 Bh[4], Bn[4];
#pragma unroll
    for(int i = 0; i < 4; i++) Bh[i] = ld8(h + (size_t)(n0 + i*16 + ln)*256 + qd*8);
#pragma unroll
    for(int c = 0; c < 8; c++){
      u16* cw = (c & 1) ? s1 : s0;
      u16* cu = (c & 1) ? u1 : u0;
      if(c < 7){
        dma4(laneWz, WST, c+1, (c & 1) ? s0 : s1);
        dma4(laneUz, 256, c+1, (c & 1) ? u0 : u1);
#pragma unroll
        for(int i = 0; i < 4; i++) Bn[i] = ld8(h + (size_t)(n0 + i*16 + ln)*256 + (c+1)*32 + qd*8);
        WAITVM(12);
      } else {
        WAITVM(0);
      }
      s16x8 Bm[4];
#pragma unroll
      for(int i = 0; i < 4; i++) Bm[i] = ldb64p(&smM[(i*16 + ln)*AST + c*32 + qd*8]);
#pragma unroll
      for(int t = 0; t < 4; t++){
        s16x8 Aw = AFRAG(cw, t);
#pragma unroll
        for(int i = 0; i < 4; i++) zacc[t][i] = MFMA(Aw, Bm[i], zacc[t][i]);
      }
#pragma unroll
      for(int t = 0; t < 4; t++){
        s16x8 Au = AFRAG(cu, t);
#pragma unroll
        for(int i = 0; i < 4; i++) zacc[t][i] = MFMA(Au, Bh[i], zacc[t][i]);
      }
      if(c < 7){
#pragma unroll
        for(int i = 0; i < 4; i++) Bh[i] = Bn[i];
      }
    }
#pragma unroll
    for(int t = 0; t < 4; t++)
#pragma unroll
      for(int i = 0; i < 4; i++) zacc[t][i] = MFMA(Aj[t], jB[i], zacc[t][i]);
  }

  // g-phase chunk-0 prefetch (no barrier needed; z's last chunk read buf1)
  const u16* laneWh = Wht + (size_t)(j0w + rw)*WST + cs;
  const u16* laneUh = Uht + (size_t)(j0w + rw)*256 + cs;
  dma4(laneWh, WST, 0, s0);
  dma4(laneUh, 256, 0, u0);

  // ================= g-phase: gacc = m@Wh + jets@Wh' + rh@Uh =================
#pragma unroll
  for(int t = 0; t < 4; t++)
#pragma unroll
    for(int i = 0; i < 4; i++) gacc[t][i] = (f32x4){0.f,0.f,0.f,0.f};
  {
    s16x8 Aj[4];
#pragma unroll
    for(int t = 0; t < 4; t++) Aj[t] = ld8(Wht + (size_t)(j0w + t*16 + ln)*WST + 256 + qd*8);
#pragma unroll
    for(int c = 0; c < 8; c++){
      u16* cw = (c & 1) ? s1 : s0;
      u16* cu = (c & 1) ? u1 : u0;
      if(c < 7){
        dma4(laneWh, WST, c+1, (c & 1) ? s0 : s1);
        dma4(laneUh, 256, c+1, (c & 1) ? u0 : u1);
        WAITVM(8);
      } else {
        WAITVM(0);
      }
      s16x8 Bm[4], Brh[4];
#pragma unroll
      for(int i = 0; i < 4; i++){
        Bm[i]  = ldb64p(&smM[(i*16 + ln)*AST + c*32 + qd*8]);
        Brh[i] = ldb64p(&smB[(i*16 + ln)*AST + c*32 + qd*8]);
      }
#pragma unroll
      for(int t = 0; t < 4; t++){
        s16x8 Aw = AFRAG(cw, t);
#pragma unroll
        for(int i = 0; i < 4; i++) gacc[t][i] = MFMA(Aw, Bm[i], gacc[t][i]);
      }
#pragma unroll
      for(int t = 0; t < 4; t++){
        s16x8 Au = AFRAG(cu, t);
#pragma unroll
        for(int i = 0; i < 4; i++) gacc[t][i] = MFMA(Au, Brh[i], gacc[t][i]);
      }
    }
#pragma unroll
    for(int t = 0; t < 4; t++)
#pragma unroll
      for(int i = 0; i < 4; i++) gacc[t][i] = MFMA(Aj[t], jB[i], gacc[t][i]);
  }
  __syncthreads();   // all smM/smB reads complete before epilogue overwrites smM

  // ================= epilogue: h_new = h + z*(tanh(g)-h) =================
#pragma unroll
  for(int t = 0; t < 4; t++){
    f32x4 bzv = *(const f32x4*)(bz + j0w + t*16 + qd*4);
    f32x4 bhv = *(const f32x4*)(bhb + j0w + t*16 + qd*4);
#pragma unroll
    for(int i = 0; i < 4; i++){
      f32x4 hv = ld4bf(h + (size_t)(n0 + i*16 + ln)*256 + j0w + t*16 + qd*4);
      f32x4 hn;
#pragma unroll
      for(int r = 0; r < 4; r++){
        float z  = fsigm(zacc[t][i][r] + bzv[r]);
        float th = ftanh(gacc[t][i][r] + bhv[r]);
        hn[r] = hv[r] + z * (th - hv[r]);
      }
      st4bf(h + (size_t)(n0 + i*16 + ln)*256 + j0w + t*16 + qd*4, hn[0], hn[1], hn[2], hn[3]);
      st4bf(&smM[(i*16 + ln)*AST + j0w + t*16 + qd*4], hn[0], hn[1], hn[2], hn[3]);
    }
  }
  // msg chunk-0 prefetch (after epilogue, before barrier)
  const u16* laneWm = Wmt + (size_t)(j0w + rw)*256 + cs;
  dma4(laneWm, 256, 0, s0);
  __syncthreads();

  // ================= msg: hm_out = h_new @ W_msg + b_msg -> [b][h][node] =================
  {
    f32x4 acc[4][4];
#pragma unroll
    for(int t = 0; t < 4; t++)
#pragma unroll
      for(int i = 0; i < 4; i++) acc[t][i] = (f32x4){0.f,0.f,0.f,0.f};
#pragma unroll
    for(int c = 0; c < 8; c++){
      u16* cur = (c & 1) ? s1 : s0;
      if(c < 7){
        dma4(laneWm, 256, c+1, (c & 1) ? s0 : s1);
        WAITVM(4);
      } else {
        WAITVM(0);
      }
      s16x8 Bf[4];
#pragma unroll
      for(int i = 0; i < 4; i++) Bf[i] = ldb64p(&smM[(i*16 + ln)*AST + c*32 + qd*8]);
#pragma unroll
      for(int t = 0; t < 4; t++){
        s16x8 A = AFRAG(cur, t);
#pragma unroll
        for(int i = 0; i < 4; i++) acc[t][i] = MFMA(A, Bf[i], acc[t][i]);
      }
    }
#pragma unroll
    for(int t = 0; t < 4; t++){
      f32x4 bmv = *(const f32x4*)(bm + j0w + t*16 + qd*4);
#pragma unroll
      for(int i = 0; i < 4; i++){
#pragma unroll
        for(int r = 0; r < 4; r++){
          hmo[(size_t)(b*256 + j0w + t*16 + qd*4 + r)*256 + nb + i*16 + ln] =
            f2bf(acc[t][i][r] + bmv[r]);
        }
      }
    }
  }
}

// ---------------------------------------------------------------------------
// Readout stage 1: t = tanh(h@W_r1 + b_r1), bf16 [BN][256]
// ---------------------------------------------------------------------------
__global__ __launch_bounds__(256,3) void k_t(
  const u16* __restrict__ h, u16* __restrict__ t_out,
  const u16* __restrict__ Wr1t, const float* __restrict__ br1)
{
  const int tid = threadIdx.x;
  const int wv = tid >> 6, lane = tid & 63, ln = lane & 15, qd = lane >> 4;
  const int n0 = blockIdx.x * 16;
  const int nodeA = n0 + ln;

  s16x8 hfr[8];
#pragma unroll
  for(int c = 0; c < 8; c++) hfr[c] = ld8(h + (size_t)nodeA*256 + c*32 + qd*8);
#pragma unroll
  for(int tp = 0; tp < 2; tp++){
    int j0 = (wv*4 + tp*2) * 16, j1 = j0 + 16;
    f32x4 a0 = {0.f,0.f,0.f,0.f}, a1 = {0.f,0.f,0.f,0.f};
#pragma unroll
    for(int c = 0; c < 8; c++){
      a0 = MFMA(ld8(Wr1t + (size_t)(j0 + ln)*256 + c*32 + qd*8), hfr[c], a0);
      a1 = MFMA(ld8(Wr1t + (size_t)(j1 + ln)*256 + c*32 + qd*8), hfr[c], a1);
    }
    f32x4 b0 = *(const f32x4*)(br1 + j0 + qd*4);
    f32x4 b1 = *(const f32x4*)(br1 + j1 + qd*4);
    st4bf(t_out + (size_t)nodeA*256 + j0 + qd*4,
          ftanh(a0[0]+b0[0]), ftanh(a0[1]+b0[1]), ftanh(a0[2]+b0[2]), ftanh(a0[3]+b0[3]));
    st4bf(t_out + (size_t)nodeA*256 + j1 + qd*4,
          ftanh(a1[0]+b1[0]), ftanh(a1[1]+b1[1]), ftanh(a1[2]+b1[2]), ftanh(a1[3]+b1[3]));
  }
}

// Readout: fused node-sum + final matmul. 64 blocks (one per batch) x 256 thr.
__global__ void k_red(const u16* __restrict__ t, const float* __restrict__ W_r2,
                      const float* __restrict__ b_r2, float* __restrict__ out){
  __shared__ float s[256];
  int b = blockIdx.x, k = threadIdx.x;
  float acc = 0.f;
  for(int n = 0; n < 256; n++) acc += bf2f(t[(size_t)(b*256 + n)*256 + k]);
  s[k] = acc;
  __syncthreads();
  int j = threadIdx.x;
  float o = 256.f * b_r2[j];
  for(int k2 = 0; k2 < 256; k2++) o += s[k2] * W_r2[k2*256 + j];
  out[b*256 + j] = o;
}

extern "C" void kernel_launch(void* const* d_in, const int* in_sizes, int n_in,
                              void* d_out, int out_size, void* d_ws, size_t ws_size,
                              hipStream_t stream)
{
  const float* jets  = (const float*)d_in[0];
  const float* dads  = (const float*)d_in[1];
  const float* W_emb = (const float*)d_in[2];
  const float* b_emb = (const float*)d_in[3];
  const float* W_msg = (const float*)d_in[4];
  const float* b_msg = (const float*)d_in[5];
  const float* Wz    = (const float*)d_in[6];
  const float* Uz    = (const float*)d_in[7];
  const float* bz    = (const float*)d_in[8];
  const float* Wr    = (const float*)d_in[9];
  const float* Ur    = (const float*)d_in[10];
  const float* br    = (const float*)d_in[11];
  const float* Wh    = (const float*)d_in[12];
  const float* Uh    = (const float*)d_in[13];
  const float* bh    = (const float*)d_in[14];
  const float* W_r1  = (const float*)d_in[15];
  const float* b_r1  = (const float*)d_in[16];
  const float* W_r2  = (const float*)d_in[17];
  const float* b_r2  = (const float*)d_in[18];

  char* ws = (char*)d_ws;
  u16* h      = (u16*)(ws);                    // 8 MB  [16384][256] bf16
  u16* hmA    = (u16*)(ws + 8388608);          // 8 MB  [64][256 h][256 node] bf16
  u16* hmB    = (u16*)(ws + 16777216);         // 8 MB
  u16* dadsb  = (u16*)(ws + 25165824);         // 8 MB  [16384][256] bf16
  u16* jp     = (u16*)(ws + 33554432);         // 1 MB  [16384][32] bf16
  u16* Wmt    = (u16*)(ws + 34603008);
  u16* Uzt    = (u16*)(ws + 34734080);
  u16* Urt    = (u16*)(ws + 34865152);
  u16* Uht    = (u16*)(ws + 34996224);
  u16* Wr1t   = (u16*)(ws + 35127296);
  u16* Wzt    = (u16*)(ws + 35258368);
  u16* Wrt    = (u16*)(ws + 35405824);
  u16* Wht    = (u16*)(ws + 35553280);
  u16* Wet    = (u16*)(ws + 35700736);
  float* outp = (float*)d_out;

  k_prep<<<8320, 256, 0, stream>>>(jets, dads, W_emb, W_msg, Wz, Uz, Wr, Ur, Wh, Uh, W_r1,
                                   jp, dadsb, Wet, Wmt, Wzt, Uzt, Wrt, Urt, Wht, Uht, Wr1t);
  k_embed<<<1024, 256, 0, stream>>>(h, hmA, jp, Wet, b_emb, Wmt, b_msg);
  for(int it = 0; it < 10; ++it){
    const u16* hin = (it & 1) ? hmB : hmA;
    u16* hout      = (it & 1) ? hmA : hmB;
    k_gru<<<256, 256, 0, stream>>>(h, hin, hout, dadsb, jp,
                                   Wzt, Wrt, Wht, Uzt, Urt, Uht, Wmt,
                                   bz, br, bh, b_msg);
  }
  // it=9 wrote hmA, so hmB is free: reuse as t-buffer
  k_t<<<1024, 256, 0, stream>>>(h, hmB, Wr1t, b_r1);
  k_red<<<64, 256, 0, stream>>>(hmB, W_r2, b_r2, outp);
}